// Round 2
// baseline (1512.824 us; speedup 1.0000x reference)
//
#include <hip/hip_runtime.h>

#define HD 256
#define KD 512

typedef _Float16 half8 __attribute__((ext_vector_type(8)));
typedef _Float16 half4v __attribute__((ext_vector_type(4)));
typedef float floatx4 __attribute__((ext_vector_type(4)));

__device__ __forceinline__ float sigmf_(float x) { return 1.f / (1.f + __expf(-x)); }
__device__ __forceinline__ float tanhf_(float x) {
  x = fminf(fmaxf(x, -15.f), 15.f);
  float e = __expf(2.f * x);
  return (e - 1.f) / (e + 1.f);
}

// ---------------------------------------------------------------------------
// prep: gate bias sums, leaf csum (=2*c_leaf), and leaf-level folded bias
// bias2[g][n] = bsum[g][n] + sum_k Wg[n][k] * 2*h_leaf[k]  (k < 256, h part)
// ---------------------------------------------------------------------------
__global__ void prep_kernel(const float* __restrict__ bf_, const float* __restrict__ b_f,
                            const float* __restrict__ bi_, const float* __restrict__ b_i,
                            const float* __restrict__ bu_, const float* __restrict__ b_u,
                            const float* __restrict__ bo_, const float* __restrict__ b_o,
                            const float* __restrict__ Wf, const float* __restrict__ Wi,
                            const float* __restrict__ Wu, const float* __restrict__ Wo,
                            float* __restrict__ bsum, float* __restrict__ bias2,
                            float* __restrict__ cleaf2)
{
  __shared__ float hl2[HD];
  int n = threadIdx.x;
  float sf = bf_[n] + b_f[n];
  float si = bi_[n] + b_i[n];
  float su = bu_[n] + b_u[n];
  float so = bo_[n] + b_o[n];
  bsum[n] = sf; bsum[HD + n] = si; bsum[2 * HD + n] = su; bsum[3 * HD + n] = so;
  float ig = 1.f / (1.f + expf(-si));
  float uu = tanhf(su);
  float cl = ig * uu;
  cleaf2[n] = cl + cl;
  float hl = (1.f / (1.f + expf(-so))) * tanhf(cl);
  hl2[n] = 2.f * hl;
  __syncthreads();
  const float* Ws[4] = {Wf, Wi, Wu, Wo};
  for (int g = 0; g < 4; ++g) {
    const float* w = Ws[g] + n * KD;
    float s = 0.f;
    for (int k = 0; k < HD; k += 4) {
      floatx4 wv = *(const floatx4*)(w + k);
      floatx4 hv = *(const floatx4*)(&hl2[k]);
      s += wv[0] * hv[0] + wv[1] * hv[1] + wv[2] * hv[2] + wv[3] * hv[3];
    }
    bias2[g * HD + n] = bsum[g * HD + n] + s;
  }
}

// ---------------------------------------------------------------------------
// convert the 4 gate weights (fp32, [256][512]) to f16 packed [g][256][512]
// ---------------------------------------------------------------------------
__global__ void wcvt_kernel(const float* __restrict__ Wf, const float* __restrict__ Wi,
                            const float* __restrict__ Wu, const float* __restrict__ Wo,
                            _Float16* __restrict__ Wh)
{
  int idx = (blockIdx.x * 256 + threadIdx.x) * 4;
  int g = idx >> 17;
  int rem = idx & ((1 << 17) - 1);
  const float* src = (g == 0) ? Wf : (g == 1) ? Wi : (g == 2) ? Wu : Wo;
  floatx4 v = *(const floatx4*)(src + rem);
  half4v o;
  o[0] = (_Float16)v[0]; o[1] = (_Float16)v[1]; o[2] = (_Float16)v[2]; o[3] = (_Float16)v[3];
  *(half4v*)(Wh + idx) = o;
}

// ---------------------------------------------------------------------------
// fused level kernel.
// block = 512 threads = 8 waves = (gate g = wave>>1) x (col-tile ct = wave&1)
// grid = (M/64, 2); n0 = blockIdx.y*128; block covers 64 rows x 128 cols.
// Inputs are PRE-PAIR-SUMMED: hsum_in[m] = h[2m]+h[2m+1] (f16),
// csum_in[m] = c[2m]+c[2m+1] (f32). Outputs likewise for the parent level.
// leaf: skip h chunk (folded into bias2), csum_in = cleaf2 broadcast.
// fin : write per-root h to hsum_out (hr) instead of pair sums.
// ---------------------------------------------------------------------------
__global__ __launch_bounds__(512, 2)
void level_kernel(const _Float16* __restrict__ hsum_in,
                  const float* __restrict__ csum_in,
                  const float* __restrict__ embed,
                  const _Float16* __restrict__ Wh,
                  const float* __restrict__ bias,
                  _Float16* __restrict__ hsum_out,
                  float* __restrict__ csum_out,
                  int l, int leaf, int fin)
{
  __shared__ __attribute__((aligned(16))) char smraw[64 * 256 * 2];
  auto As = (_Float16(*)[256])smraw;       // 64 rows x 256 f16, XOR-swizzled groups
  auto Zs = (float(*)[8][128])smraw;       // [4 gates][8 rows][128 cols], aliased

  const int cnt = 1 << l;
  const int cs = (2 << l) - 1;
  const int m0 = blockIdx.x * 64;
  const int n0 = blockIdx.y * 128;
  const int t = threadIdx.x;
  const int wave = t >> 6;
  const int lane = t & 63;
  const int lm = lane & 15;
  const int quad = lane >> 4;
  const int g = wave >> 1;
  const int ct = wave & 1;

  floatx4 acc[4][4] = {};

  // staging mapping: row sr = t>>3 (0..63), granule lane c8 = t&7
  const int sr = t >> 3;
  const int c8 = t & 7;
  const int sm = m0 + sr;
  const int sb = sm >> l;
  const int sj = sm & (cnt - 1);
  const long ebase = ((long)sb * 1023 + cs + 2 * sj) * 256;

  const _Float16* wg = Wh + (long)(g * HD + n0 + ct * 64) * KD;

  auto gemm_chunk = [&](int kbase) {
#pragma unroll
    for (int ks = 0; ks < 8; ++ks) {
      half8 bfr[4], afr[4];
#pragma unroll
      for (int nt = 0; nt < 4; ++nt)
        bfr[nt] = *(const half8*)(wg + (long)(nt * 16 + lm) * KD + kbase + ks * 32 + quad * 8);
#pragma unroll
      for (int mt = 0; mt < 4; ++mt) {
        int row = mt * 16 + lm;
        afr[mt] = *(const half8*)(&As[row][((ks * 4 + quad) ^ (row & 7)) * 8]);
      }
#pragma unroll
      for (int mt = 0; mt < 4; ++mt)
#pragma unroll
        for (int nt = 0; nt < 4; ++nt)
          acc[mt][nt] = __builtin_amdgcn_mfma_f32_16x16x32_f16(afr[mt], bfr[nt], acc[mt][nt], 0, 0, 0);
    }
  };

  if (!leaf) {
    // chunk 0: pre-summed child h (k 0..255) — pure f16 copy
    const _Float16* hp = hsum_in + (long)sm * HD;
#pragma unroll
    for (int gi = 0; gi < 4; ++gi) {
      int gl = gi * 8 + c8;
      half8 v = __builtin_nontemporal_load((const half8*)(hp + gl * 8));
      *(half8*)(&As[sr][((gl ^ (sr & 7)) * 8)]) = v;
    }
    __syncthreads();
    gemm_chunk(0);
    __syncthreads();
  }

  // chunk 1: embed pair-sum (k 256..511 of W)
  {
    const float* e0 = embed + ebase;
    const float* e1 = e0 + 256;
#pragma unroll
    for (int gi = 0; gi < 4; ++gi) {
      int gl = gi * 8 + c8;
      floatx4 x0 = __builtin_nontemporal_load((const floatx4*)(e0 + gl * 8));
      floatx4 x1 = __builtin_nontemporal_load((const floatx4*)(e0 + gl * 8 + 4));
      floatx4 y0 = __builtin_nontemporal_load((const floatx4*)(e1 + gl * 8));
      floatx4 y1 = __builtin_nontemporal_load((const floatx4*)(e1 + gl * 8 + 4));
      half8 s;
#pragma unroll
      for (int e = 0; e < 4; ++e) { s[e] = (_Float16)(x0[e] + y0[e]); s[4 + e] = (_Float16)(x1[e] + y1[e]); }
      *(half8*)(&As[sr][((gl ^ (sr & 7)) * 8)]) = s;
    }
  }
  __syncthreads();
  gemm_chunk(256);

  // ---------------- epilogue ----------------
  // 8 slabs of 8 rows; Zs aliases As.
  const int ep_p = t >> 7;        // 0..3 parent-slot within slab
  const int ep_c = t & 127;       // col within the block's 128-col slice
  const int coln = n0 + ep_c;
  float bb[4];
#pragma unroll
  for (int g2 = 0; g2 < 4; ++g2) bb[g2] = bias[g2 * HD + coln];
  const float cleafv = leaf ? csum_in[coln] : 0.f;

#pragma unroll 1
  for (int s = 0; s < 8; ++s) {
    __syncthreads();
    const int mt = s >> 1, hh = s & 1;
    if ((quad >> 1) == hh) {
      const int rb = (quad & 1) * 4;
#pragma unroll
      for (int nt = 0; nt < 4; ++nt)
#pragma unroll
        for (int e = 0; e < 4; ++e)
          Zs[g][rb + e][ct * 64 + nt * 16 + lm] = acc[mt][nt][e];
    }
    __syncthreads();

    const int mmA = m0 + 8 * s + 2 * ep_p;
    float csA, csB;
    if (leaf) { csA = cleafv; csB = cleafv; }
    else {
      csA = __builtin_nontemporal_load(csum_in + (long)mmA * HD + coln);
      csB = __builtin_nontemporal_load(csum_in + (long)(mmA + 1) * HD + coln);
    }
    float zA[4], zB[4];
#pragma unroll
    for (int g2 = 0; g2 < 4; ++g2) {
      zA[g2] = Zs[g2][2 * ep_p][ep_c] + bb[g2];
      zB[g2] = Zs[g2][2 * ep_p + 1][ep_c] + bb[g2];
    }
    float fA = sigmf_(zA[0]), iA = sigmf_(zA[1]), uA = tanhf_(zA[2]), oA = sigmf_(zA[3]);
    float cA_ = iA * uA + fA * csA;
    float hA_ = oA * tanhf_(cA_);
    float fB = sigmf_(zB[0]), iB = sigmf_(zB[1]), uB = tanhf_(zB[2]), oB = sigmf_(zB[3]);
    float cB_ = iB * uB + fB * csB;
    float hB_ = oB * tanhf_(cB_);

    if (fin) {
      hsum_out[(long)mmA * HD + coln] = (_Float16)hA_;
      hsum_out[(long)(mmA + 1) * HD + coln] = (_Float16)hB_;
    } else {
      const long pr = mmA >> 1;
      hsum_out[pr * HD + coln] = (_Float16)(hA_ + hB_);
      csum_out[pr * HD + coln] = cA_ + cB_;
    }
  }
}

// ---------------------------------------------------------------------------
// head: tiny 128x256 @ 256x256 matmuls, one block per batch row
// ---------------------------------------------------------------------------
__global__ void head12_kernel(const _Float16* __restrict__ hr,
                              const float* __restrict__ W1, const float* __restrict__ bl1,
                              const float* __restrict__ W2, const float* __restrict__ bl2,
                              float* __restrict__ t1, float* __restrict__ t2)
{
  __shared__ float a[HD];
  int b = blockIdx.x, n = threadIdx.x;
  a[n] = (float)hr[b * HD + n];
  __syncthreads();
  const float* w1 = W1 + n * HD;
  const float* w2 = W2 + n * HD;
  float s1 = bl1[n], s2 = bl2[n];
  for (int k = 0; k < HD; k += 4) {
    floatx4 av = *(const floatx4*)(&a[k]);
    floatx4 w1v = *(const floatx4*)(w1 + k);
    floatx4 w2v = *(const floatx4*)(w2 + k);
#pragma unroll
    for (int e = 0; e < 4; ++e) { s1 += av[e] * w1v[e]; s2 += av[e] * w2v[e]; }
  }
  t1[b * HD + n] = tanhf_(s1);
  t2[b * HD + n] = fmaxf(s2, 0.f);
}

__global__ void head3_kernel(const float* __restrict__ t2, const float* __restrict__ W3,
                             const float* __restrict__ bl3, const float* __restrict__ t1,
                             float* __restrict__ sb)
{
  __shared__ float a[HD];
  int b = blockIdx.x, n = threadIdx.x;
  a[n] = t2[b * HD + n];
  __syncthreads();
  const float* w = W3 + n * HD;
  float s = bl3[n];
  for (int k = 0; k < HD; k += 4) {
    floatx4 av = *(const floatx4*)(&a[k]);
    floatx4 wv = *(const floatx4*)(w + k);
#pragma unroll
    for (int e = 0; e < 4; ++e) s += av[e] * wv[e];
  }
  sb[b * HD + n] = t1[b * HD + n] + s;
}

__global__ void head4_kernel(const float* __restrict__ sv, const float* __restrict__ W4,
                             const float* __restrict__ bl4, float* __restrict__ out)
{
  __shared__ float a[HD];
  int b = blockIdx.x, n = threadIdx.x;
  a[n] = sv[b * HD + n];
  __syncthreads();
  const float* w = W4 + n * HD;
  float s = bl4[n];
  for (int k = 0; k < HD; k += 4) {
    floatx4 av = *(const floatx4*)(&a[k]);
    floatx4 wv = *(const floatx4*)(w + k);
#pragma unroll
    for (int e = 0; e < 4; ++e) s += av[e] * wv[e];
  }
  out[b * HD + n] = fmaxf(s, 0.f);
}

// ---------------------------------------------------------------------------
extern "C" void kernel_launch(void* const* d_in, const int* in_sizes, int n_in,
                              void* d_out, int out_size, void* d_ws, size_t ws_size,
                              hipStream_t stream)
{
  (void)in_sizes; (void)n_in; (void)out_size; (void)ws_size;
  const float* embed = (const float*)d_in[0];
  const float* Wf  = (const float*)d_in[1];
  const float* bf_ = (const float*)d_in[2];
  const float* b_f = (const float*)d_in[3];
  const float* Wi  = (const float*)d_in[4];
  const float* bi_ = (const float*)d_in[5];
  const float* b_i = (const float*)d_in[6];
  const float* Wu  = (const float*)d_in[7];
  const float* bu_ = (const float*)d_in[8];
  const float* b_u = (const float*)d_in[9];
  const float* Wo  = (const float*)d_in[10];
  const float* bo_ = (const float*)d_in[11];
  const float* b_o = (const float*)d_in[12];
  const float* W1  = (const float*)d_in[13];
  const float* bl1 = (const float*)d_in[14];
  const float* W2  = (const float*)d_in[15];
  const float* bl2 = (const float*)d_in[16];
  const float* W3  = (const float*)d_in[17];
  const float* bl3 = (const float*)d_in[18];
  const float* W4  = (const float*)d_in[19];
  const float* bl4 = (const float*)d_in[20];

  char* ws = (char*)d_ws;
  _Float16* Wh   = (_Float16*)(ws);                 // 1,048,576 B
  float* bsum    = (float*)(ws + 1048576);          // 4 KB
  float* bias2   = (float*)(ws + 1052672);          // 4 KB
  float* cleaf2  = (float*)(ws + 1056768);          // 1 KB
  _Float16* hr   = (_Float16*)(ws + 1057792);       // 64 KB  (root h, f16)
  float* t1      = (float*)(ws + 1123328);          // 128 KB
  float* t2      = (float*)(ws + 1254400);          // 128 KB
  float* sbuf    = (float*)(ws + 1385472);          // 128 KB
  _Float16* HsA  = (_Float16*)(ws + 1516544);       // 8,388,608 B  (max: 16384x256 f16)
  float* CsA     = (float*)(ws + 9905152);          // 16,777,216 B (max: 16384x256 f32)
  _Float16* HsB  = (_Float16*)(ws + 26682368);      // 8,388,608 B
  float* CsB     = (float*)(ws + 35070976);         // 16,777,216 B -> end 51,848,192 B

  prep_kernel<<<dim3(1), dim3(256), 0, stream>>>(bf_, b_f, bi_, b_i, bu_, b_u, bo_, b_o,
                                                 Wf, Wi, Wu, Wo, bsum, bias2, cleaf2);
  wcvt_kernel<<<dim3(512), dim3(256), 0, stream>>>(Wf, Wi, Wu, Wo, Wh);

  _Float16* hbufs[2] = {HsA, HsB};
  float* cbufs[2] = {CsA, CsB};
  int pp = 0;
  const _Float16* hin = nullptr;
  const float* cin = cleaf2;
  for (int l = 8; l >= 0; --l) {
    const int leaf = (l == 8);
    const int fin = (l == 0);
    _Float16* hout = fin ? hr : hbufs[pp];
    float* cout = cbufs[pp];
    dim3 grid(2 << l, 2);
    level_kernel<<<grid, dim3(512), 0, stream>>>(hin, cin, embed, Wh,
                                                 leaf ? bias2 : bsum,
                                                 hout, cout, l, leaf, fin);
    hin = hbufs[pp];
    cin = cbufs[pp];
    pp ^= 1;
  }

  head12_kernel<<<dim3(128), dim3(256), 0, stream>>>(hr, W1, bl1, W2, bl2, t1, t2);
  head3_kernel<<<dim3(128), dim3(256), 0, stream>>>(t2, W3, bl3, t1, sbuf);
  head4_kernel<<<dim3(128), dim3(256), 0, stream>>>(sbuf, W4, bl4, (float*)d_out);
}